// Round 5
// baseline (1131.439 us; speedup 1.0000x reference)
//
#include <hip/hip_runtime.h>
#include <stdint.h>

typedef __attribute__((ext_vector_type(8))) short short8;
typedef __attribute__((ext_vector_type(4))) float f32x4;

typedef unsigned short u16;

constexpr int S_LEN = 2048;
constexpr int DH    = 128;

__device__ __forceinline__ u16 f2bf(float f) {
    union { float f; unsigned u; } v; v.f = f;
    unsigned r = v.u + 0x7FFFu + ((v.u >> 16) & 1u);
    return (u16)(r >> 16);
}
__device__ __forceinline__ float bf2f(u16 h) {
    union { unsigned u; float f; } v; v.u = ((unsigned)h) << 16;
    return v.f;
}

// Load 8 consecutive logical elements as bf16x8, from either an fp32 or a
// bf16 buffer (flag-selected, wave-uniform branch).
__device__ __forceinline__ short8 ld8(const void* p, size_t eoff, bool isf32) {
    if (isf32) {
        const float* f = (const float*)p + eoff;
        f32x4 a = *(const f32x4*)f;
        f32x4 b = *(const f32x4*)(f + 4);
        short8 r;
        r[0] = (short)f2bf(a[0]); r[1] = (short)f2bf(a[1]);
        r[2] = (short)f2bf(a[2]); r[3] = (short)f2bf(a[3]);
        r[4] = (short)f2bf(b[0]); r[5] = (short)f2bf(b[1]);
        r[6] = (short)f2bf(b[2]); r[7] = (short)f2bf(b[3]);
        return r;
    }
    return *(const short8*)((const u16*)p + eoff);
}

// ---------- input dtype autodetect ----------
// fp32 array: even u16 slots are low mantissa halves -> random exponent field.
// bf16 array: even u16 slots are real bf16 N(0,1) values -> exponent ~110..140.
__global__ void detect_dtype(const void* x, int* flag) {
    if (threadIdx.x == 0 && blockIdx.x == 0) {
        const u16* p = (const u16*)x;
        int sane = 0;
        for (int i = 0; i < 64; ++i) {
            int e = (p[2 * i] >> 7) & 0xFF;
            if (e >= 110 && e <= 140) ++sane;
        }
        *flag = (sane >= 32) ? 0 : 1;   // 1 = fp32 inputs
    }
}

// ================= QKV GEMM =================
// C[4096 x 6144] = x[4096 x 2048] * Wqkv[2048 x 6144]  (B natural K-major)
// block 256 = 4 waves (2x2), 128x128 tile, MFMA 16x16x32 bf16.
// B staged into LDS transposed: lB[n][k], n-stride 40 u16.
__global__ __launch_bounds__(256) void gemm_qkv(
        const void* __restrict__ A, const void* __restrict__ B,
        const int* __restrict__ flag,
        u16* __restrict__ Qo, u16* __restrict__ Ko, u16* __restrict__ Vo) {
    __shared__ __align__(16) u16 lA[128 * 32];
    __shared__ __align__(16) u16 lB[128 * 40];
    const bool isf32 = (*flag != 0);
    const int tid = threadIdx.x;
    const int lane = tid & 63, wave = tid >> 6;
    const int quad = lane >> 4, l16 = lane & 15;
    const int wm = wave >> 1, wn = wave & 1;
    const int m0 = blockIdx.y * 128, n0 = blockIdx.x * 128;
    f32x4 acc[4][4] = {};
    const int rbase = tid >> 2;          // 0..63
    const int cofs  = (tid & 3) * 8;     // k offset within 32

    for (int k0 = 0; k0 < 2048; k0 += 32) {
#pragma unroll
        for (int it = 0; it < 2; ++it) {
            int row = it * 64 + rbase;
            short8 va = ld8(A, (size_t)(m0 + row) * 2048 + k0 + cofs, isf32);
            *(short8*)&lA[(it * 256 + tid) * 8] = va;
        }
#pragma unroll
        for (int p = 0; p < 2; ++p) {
            int kr = p * 16 + (tid >> 4);        // 0..31
            int cg = tid & 15;                   // n-chunk
            short8 vb = ld8(B, (size_t)(k0 + kr) * 6144 + n0 + cg * 8, isf32);
#pragma unroll
            for (int e = 0; e < 8; ++e)
                lB[(cg * 8 + e) * 40 + kr] = (u16)vb[e];
        }
        __syncthreads();
        short8 af[4], bf[4];
#pragma unroll
        for (int i = 0; i < 4; ++i) {
            af[i] = *(const short8*)&lA[(wm * 64 + i * 16 + l16) * 32 + quad * 8];
            bf[i] = *(const short8*)&lB[(wn * 64 + i * 16 + l16) * 40 + quad * 8];
        }
#pragma unroll
        for (int im = 0; im < 4; ++im)
#pragma unroll
            for (int in = 0; in < 4; ++in)
                acc[im][in] = __builtin_amdgcn_mfma_f32_16x16x32_bf16(af[im], bf[in], acc[im][in], 0, 0, 0);
        __syncthreads();
    }
#pragma unroll
    for (int im = 0; im < 4; ++im) {
        int r0r = m0 + wm * 64 + im * 16 + quad * 4;
#pragma unroll
        for (int in = 0; in < 4; ++in) {
            int cc = n0 + wn * 64 + in * 16 + l16;
            int which = cc >> 11, hd = (cc >> 7) & 15, dh = cc & 127;
            u16* dst = which == 0 ? Qo : (which == 1 ? Ko : Vo);
#pragma unroll
            for (int rg = 0; rg < 4; ++rg) {
                int rr = r0r + rg;
                int b = rr >> 11, s = rr & 2047;
                dst[(size_t)((b * 16 + hd) * 2048 + s) * 128 + dh] = f2bf(acc[im][in][rg]);
            }
        }
    }
}

// ================= flash attention (causal) =================
// grid (qt=32, bh=32); block 256 = 4 waves; wave w owns q rows qt*64+w*16..+15.
// Q,K,V: internal bf16 [BH][S][DH]. O overwrites Q in place.
__global__ __launch_bounds__(256) void attn_kern(
        u16* __restrict__ QOp, const u16* __restrict__ Kp,
        const u16* __restrict__ Vp) {
    __shared__ __align__(16) u16 Pl[4][16 * 72];   // per-wave P, row stride 72
    __shared__ __align__(16) u16 lV[128 * 72];     // V-tile transposed [dh][key]
    const int tid = threadIdx.x, lane = tid & 63, wave = tid >> 6;
    const int quad = lane >> 4, l16 = lane & 15;
    const int qt = blockIdx.x, bh = blockIdx.y;
    const int qbase = qt * 64 + wave * 16;
    u16* Qh = QOp + (size_t)bh * S_LEN * DH;
    const u16* Kh = Kp + (size_t)bh * S_LEN * DH;
    const u16* Vh = Vp + (size_t)bh * S_LEN * DH;
    u16* Pw = Pl[wave];

    short8 aq[4];
#pragma unroll
    for (int kk = 0; kk < 4; ++kk)
        aq[kk] = *(const short8*)&Qh[(size_t)(qbase + l16) * 128 + kk * 32 + quad * 8];

    f32x4 acc_o[8] = {};
    float m_i[4], l_i[4];
#pragma unroll
    for (int r = 0; r < 4; ++r) { m_i[r] = -1e9f; l_i[r] = 0.f; }
    const float scale = 0.08838834764831845f;  // 1/sqrt(128)

    for (int kt = 0; kt <= qt; ++kt) {
        // stage V-tile [64 keys][128 dh] -> lV[dh][key]
#pragma unroll
        for (int it = 0; it < 4; ++it) {
            int chunk = it * 256 + tid;          // 0..1023
            int r = chunk >> 4, cg = chunk & 15;
            short8 vv = *(const short8*)&Vh[(size_t)(kt * 64 + r) * 128 + cg * 8];
#pragma unroll
            for (int e = 0; e < 8; ++e)
                lV[(cg * 8 + e) * 72 + r] = (u16)vv[e];
        }
        // QK^T
        f32x4 sa[4] = {};
#pragma unroll
        for (int nt = 0; nt < 4; ++nt)
#pragma unroll
            for (int kk = 0; kk < 4; ++kk) {
                short8 bk = *(const short8*)&Kh[(size_t)(kt * 64 + nt * 16 + l16) * 128 + kk * 32 + quad * 8];
                sa[nt] = __builtin_amdgcn_mfma_f32_16x16x32_bf16(aq[kk], bk, sa[nt], 0, 0, 0);
            }
        __syncthreads();   // lV visible
        float sv[4][4];
        float mt[4] = {-1e9f, -1e9f, -1e9f, -1e9f};
#pragma unroll
        for (int nt = 0; nt < 4; ++nt) {
            int kg = kt * 64 + nt * 16 + l16;
#pragma unroll
            for (int rg = 0; rg < 4; ++rg) {
                float s = sa[nt][rg] * scale;
                int qg = qbase + quad * 4 + rg;
                if (kg > qg) s = -1e9f;
                sv[nt][rg] = s;
                mt[rg] = fmaxf(mt[rg], s);
            }
        }
        float alpha[4];
#pragma unroll
        for (int rg = 0; rg < 4; ++rg) {
#pragma unroll
            for (int off = 8; off >= 1; off >>= 1)
                mt[rg] = fmaxf(mt[rg], __shfl_xor(mt[rg], off));
            float mn = fmaxf(m_i[rg], mt[rg]);
            alpha[rg] = __expf(m_i[rg] - mn);
            m_i[rg] = mn;
            float rs = 0.f;
#pragma unroll
            for (int nt = 0; nt < 4; ++nt) {
                float p = __expf(sv[nt][rg] - mn);
                sv[nt][rg] = p;
                rs += p;
            }
#pragma unroll
            for (int off = 8; off >= 1; off >>= 1)
                rs += __shfl_xor(rs, off);
            l_i[rg] = l_i[rg] * alpha[rg] + rs;
        }
#pragma unroll
        for (int d = 0; d < 8; ++d)
#pragma unroll
            for (int rg = 0; rg < 4; ++rg)
                acc_o[d][rg] *= alpha[rg];
        // P (C-layout) -> per-wave LDS -> A-layout
#pragma unroll
        for (int nt = 0; nt < 4; ++nt)
#pragma unroll
            for (int rg = 0; rg < 4; ++rg)
                Pw[(quad * 4 + rg) * 72 + nt * 16 + l16] = f2bf(sv[nt][rg]);
        short8 ap0 = *(const short8*)&Pw[l16 * 72 + quad * 8];
        short8 ap1 = *(const short8*)&Pw[l16 * 72 + 32 + quad * 8];
#pragma unroll
        for (int d = 0; d < 8; ++d) {
            short8 bv0 = *(const short8*)&lV[(d * 16 + l16) * 72 + quad * 8];
            acc_o[d] = __builtin_amdgcn_mfma_f32_16x16x32_bf16(ap0, bv0, acc_o[d], 0, 0, 0);
            short8 bv1 = *(const short8*)&lV[(d * 16 + l16) * 72 + 32 + quad * 8];
            acc_o[d] = __builtin_amdgcn_mfma_f32_16x16x32_bf16(ap1, bv1, acc_o[d], 0, 0, 0);
        }
        __syncthreads();   // protect lV/Pl before next iteration
    }
#pragma unroll
    for (int d = 0; d < 8; ++d)
#pragma unroll
        for (int rg = 0; rg < 4; ++rg) {
            int s = qbase + quad * 4 + rg;
            Qh[(size_t)s * 128 + d * 16 + l16] = f2bf(acc_o[d][rg] / l_i[rg]);
        }
}

// ================= proj GEMM =================
// out[4096 x 2048] = O[4096 x 2048] * Wproj[2048 x 2048] + bias.
// OUTPUT IS FP32 (reference returns float32; d_out is float*).
__global__ __launch_bounds__(256) void gemm_proj(
        const u16* __restrict__ QO, const void* __restrict__ B,
        const void* __restrict__ bias, const int* __restrict__ flag,
        float* __restrict__ out) {
    __shared__ __align__(16) u16 lA[128 * 32];
    __shared__ __align__(16) u16 lB[128 * 40];
    const bool isf32 = (*flag != 0);
    const int tid = threadIdx.x;
    const int lane = tid & 63, wave = tid >> 6;
    const int quad = lane >> 4, l16 = lane & 15;
    const int wm = wave >> 1, wn = wave & 1;
    const int m0 = blockIdx.y * 128, n0 = blockIdx.x * 128;
    f32x4 acc[4][4] = {};
    const int rbase = tid >> 2;
    const int cofs  = (tid & 3) * 8;

    for (int k0 = 0; k0 < 2048; k0 += 32) {
#pragma unroll
        for (int it = 0; it < 2; ++it) {
            int row = m0 + it * 64 + rbase;       // global m
            int b = row >> 11, s = row & 2047;
            int k = k0 + cofs, h = k >> 7, dh = k & 127;
            short8 va = *(const short8*)(QO + ((size_t)(b * 16 + h) * 2048 + s) * 128 + dh);
            *(short8*)&lA[(it * 256 + tid) * 8] = va;
        }
#pragma unroll
        for (int p = 0; p < 2; ++p) {
            int kr = p * 16 + (tid >> 4);
            int cg = tid & 15;
            short8 vb = ld8(B, (size_t)(k0 + kr) * 2048 + n0 + cg * 8, isf32);
#pragma unroll
            for (int e = 0; e < 8; ++e)
                lB[(cg * 8 + e) * 40 + kr] = (u16)vb[e];
        }
        __syncthreads();
        short8 af[4], bf[4];
#pragma unroll
        for (int i = 0; i < 4; ++i) {
            af[i] = *(const short8*)&lA[(wm * 64 + i * 16 + l16) * 32 + quad * 8];
            bf[i] = *(const short8*)&lB[(wn * 64 + i * 16 + l16) * 40 + quad * 8];
        }
#pragma unroll
        for (int im = 0; im < 4; ++im)
#pragma unroll
            for (int in = 0; in < 4; ++in)
                acc[im][in] = __builtin_amdgcn_mfma_f32_16x16x32_bf16(af[im], bf[in], acc[im][in], 0, 0, 0);
        __syncthreads();
    }
#pragma unroll
    for (int im = 0; im < 4; ++im) {
        int r0r = m0 + wm * 64 + im * 16 + quad * 4;
#pragma unroll
        for (int in = 0; in < 4; ++in) {
            int cc = n0 + wn * 64 + in * 16 + l16;
            float bv = isf32 ? ((const float*)bias)[cc] : bf2f(((const u16*)bias)[cc]);
#pragma unroll
            for (int rg = 0; rg < 4; ++rg)
                out[(size_t)(r0r + rg) * 2048 + cc] = acc[im][in][rg] + bv;
        }
    }
}

extern "C" void kernel_launch(void* const* d_in, const int* in_sizes, int n_in,
                              void* d_out, int out_size, void* d_ws, size_t ws_size,
                              hipStream_t stream) {
    // match inputs by element count (all distinct) — immune to ordering
    const void *x = nullptr, *Wqkv = nullptr, *Wproj = nullptr, *bproj = nullptr;
    for (int i = 0; i < n_in; ++i) {
        int sz = in_sizes[i];
        if      (sz == 2 * 2048 * 2048) x     = d_in[i];
        else if (sz == 2048 * 6144)     Wqkv  = d_in[i];
        else if (sz == 2048 * 2048)     Wproj = d_in[i];
        else if (sz == 2048)            bproj = d_in[i];
    }
    float* out = (float*)d_out;

    // ws: [flag int][pad to 1KB][QO 16.8MB][K 16.8MB][V 16.8MB]
    int* flag = (int*)d_ws;
    u16* QOb  = (u16*)d_ws + 512;
    u16* Kb   = QOb + (size_t)32 * 2048 * 128;
    u16* Vb   = Kb  + (size_t)32 * 2048 * 128;

    detect_dtype<<<dim3(1), dim3(64), 0, stream>>>(x, flag);
    gemm_qkv<<<dim3(48, 32, 1), dim3(256, 1, 1), 0, stream>>>(x, Wqkv, flag, QOb, Kb, Vb);
    attn_kern<<<dim3(32, 32, 1), dim3(256, 1, 1), 0, stream>>>(QOb, Kb, Vb);
    gemm_proj<<<dim3(16, 32, 1), dim3(256, 1, 1), 0, stream>>>(QOb, Wproj, bproj, flag, out);
}

// Round 6
// 792.966 us; speedup vs baseline: 1.4268x; 1.4268x over previous
//
#include <hip/hip_runtime.h>
#include <stdint.h>

typedef __attribute__((ext_vector_type(8))) short short8;
typedef __attribute__((ext_vector_type(4))) float f32x4;
typedef __attribute__((ext_vector_type(4))) unsigned short u16x4;

typedef unsigned short u16;

constexpr int S_LEN = 2048;
constexpr int DH    = 128;

__device__ __forceinline__ u16 f2bf(float f) {
    union { float f; unsigned u; } v; v.f = f;
    unsigned r = v.u + 0x7FFFu + ((v.u >> 16) & 1u);
    return (u16)(r >> 16);
}
__device__ __forceinline__ void gl_lds16(const void* g, void* l) {
    __builtin_amdgcn_global_load_lds((const __attribute__((address_space(1))) void*)g,
                                     (__attribute__((address_space(3))) void*)l,
                                     16, 0, 0);
}

// ---------- fp32 -> bf16 bulk convert (8 elems/thread, vectorized) ----------
__global__ __launch_bounds__(256) void convx(const float* __restrict__ src,
                                             u16* __restrict__ dst) {
    size_t i = ((size_t)blockIdx.x * 256 + threadIdx.x) * 8;
    f32x4 a = *(const f32x4*)(src + i);
    f32x4 b = *(const f32x4*)(src + i + 4);
    short8 r;
    r[0] = (short)f2bf(a[0]); r[1] = (short)f2bf(a[1]);
    r[2] = (short)f2bf(a[2]); r[3] = (short)f2bf(a[3]);
    r[4] = (short)f2bf(b[0]); r[5] = (short)f2bf(b[1]);
    r[6] = (short)f2bf(b[2]); r[7] = (short)f2bf(b[3]);
    *(short8*)(dst + i) = r;
}

// ---------- fp32 [rows][cols] -> bf16 transposed [cols][rows] ----------
__global__ void convT(const float* __restrict__ src, u16* __restrict__ dst,
                      int rows, int cols) {
    __shared__ u16 tile[32][33];
    int c0 = blockIdx.x * 32, r0 = blockIdx.y * 32;
    int tx = threadIdx.x, ty = threadIdx.y;
#pragma unroll
    for (int i = 0; i < 32; i += 8)
        tile[ty + i][tx] = f2bf(src[(size_t)(r0 + ty + i) * cols + c0 + tx]);
    __syncthreads();
#pragma unroll
    for (int i = 0; i < 32; i += 8)
        dst[(size_t)(c0 + ty + i) * rows + r0 + tx] = tile[tx][ty + i];
}

// ================= QKV GEMM (m97 structure) =================
// C[4096 x 6144] = xb[4096 x 2048] * WqkvT[6144 x 2048]^T, both bf16 K-major.
// global_load_lds 16B staging, ds_read_b128 fragments, 16 MFMA/k-iter.
// Epilogue: Q,K natural [BH][S][DH]; V written transposed VT [BH][DH][S].
__global__ __launch_bounds__(256) void gemm_qkv(
        const u16* __restrict__ A, const u16* __restrict__ BT,
        u16* __restrict__ Qo, u16* __restrict__ Ko, u16* __restrict__ VTo) {
    __shared__ __align__(16) u16 lA[128 * 32];
    __shared__ __align__(16) u16 lB[128 * 32];
    const int tid = threadIdx.x;
    const int lane = tid & 63, wave = tid >> 6;
    const int quad = lane >> 4, l16 = lane & 15;
    const int wm = wave >> 1, wn = wave & 1;
    const int m0 = blockIdx.y * 128, n0 = blockIdx.x * 128;
    f32x4 acc[4][4] = {};
    const int rbase = tid >> 2;          // 0..63
    const int cofs  = (tid & 3) * 8;     // k offset within 32

    for (int k0 = 0; k0 < 2048; k0 += 32) {
#pragma unroll
        for (int it = 0; it < 2; ++it) {
            int row = it * 64 + rbase;
            gl_lds16(A  + (size_t)(m0 + row) * 2048 + k0 + cofs, &lA[(it * 256 + tid) * 8]);
            gl_lds16(BT + (size_t)(n0 + row) * 2048 + k0 + cofs, &lB[(it * 256 + tid) * 8]);
        }
        __syncthreads();
        short8 af[4], bf[4];
#pragma unroll
        for (int i = 0; i < 4; ++i) {
            af[i] = *(const short8*)&lA[(wm * 64 + i * 16 + l16) * 32 + quad * 8];
            bf[i] = *(const short8*)&lB[(wn * 64 + i * 16 + l16) * 32 + quad * 8];
        }
#pragma unroll
        for (int im = 0; im < 4; ++im)
#pragma unroll
            for (int in = 0; in < 4; ++in)
                acc[im][in] = __builtin_amdgcn_mfma_f32_16x16x32_bf16(af[im], bf[in], acc[im][in], 0, 0, 0);
        __syncthreads();
    }
#pragma unroll
    for (int im = 0; im < 4; ++im) {
        int r0r = m0 + wm * 64 + im * 16 + quad * 4;
        int b = r0r >> 11, s0 = r0r & 2047;      // 4 consecutive rows share b
#pragma unroll
        for (int in = 0; in < 4; ++in) {
            int cc = n0 + wn * 64 + in * 16 + l16;
            int which = cc >> 11, hd = (cc >> 7) & 15, dh = cc & 127;
            if (which < 2) {
                u16* dst = which == 0 ? Qo : Ko;
#pragma unroll
                for (int rg = 0; rg < 4; ++rg)
                    dst[(size_t)((b * 16 + hd) * 2048 + s0 + rg) * 128 + dh] = f2bf(acc[im][in][rg]);
            } else {
                u16x4 v;
#pragma unroll
                for (int rg = 0; rg < 4; ++rg) v[rg] = f2bf(acc[im][in][rg]);
                *(u16x4*)&VTo[((size_t)(b * 16 + hd) * 128 + dh) * 2048 + s0] = v;
            }
        }
    }
}

// ================= flash attention (causal, barrier-free) =================
// grid (32,32); qt = 31-blockIdx.x (long blocks dispatch first).
// block 256 = 4 waves; wave w owns q rows qt*64+w*16..+15.
// Q,K natural [BH][S][DH]; VT [BH][DH][S]; O overwrites Q in place.
// P round-trip uses per-wave LDS only -> no __syncthreads anywhere.
__global__ __launch_bounds__(256) void attn_kern(
        u16* __restrict__ QOp, const u16* __restrict__ Kp,
        const u16* __restrict__ VTp) {
    __shared__ __align__(16) u16 Pl[4][16 * 72];   // per-wave P, row stride 72
    const int tid = threadIdx.x, lane = tid & 63, wave = tid >> 6;
    const int quad = lane >> 4, l16 = lane & 15;
    const int qt = 31 - blockIdx.x, bh = blockIdx.y;
    const int qbase = qt * 64 + wave * 16;
    u16* Qh = QOp + (size_t)bh * S_LEN * DH;
    const u16* Kh = Kp + (size_t)bh * S_LEN * DH;
    const u16* VTh = VTp + (size_t)bh * DH * S_LEN;
    u16* Pw = Pl[wave];

    short8 aq[4];
#pragma unroll
    for (int kk = 0; kk < 4; ++kk)
        aq[kk] = *(const short8*)&Qh[(size_t)(qbase + l16) * 128 + kk * 32 + quad * 8];

    f32x4 acc_o[8] = {};
    float m_i[4], l_i[4];
#pragma unroll
    for (int r = 0; r < 4; ++r) { m_i[r] = -1e9f; l_i[r] = 0.f; }
    const float scale = 0.08838834764831845f;  // 1/sqrt(128)

    for (int kt = 0; kt <= qt; ++kt) {
        // QK^T: K natural, b[j]=K[key=l16][dh=quad*8+j] contiguous 16B/lane
        f32x4 sa[4] = {};
#pragma unroll
        for (int nt = 0; nt < 4; ++nt)
#pragma unroll
            for (int kk = 0; kk < 4; ++kk) {
                short8 bk = *(const short8*)&Kh[(size_t)(kt * 64 + nt * 16 + l16) * 128 + kk * 32 + quad * 8];
                sa[nt] = __builtin_amdgcn_mfma_f32_16x16x32_bf16(aq[kk], bk, sa[nt], 0, 0, 0);
            }
        float sv[4][4];
        float mt[4] = {-1e9f, -1e9f, -1e9f, -1e9f};
#pragma unroll
        for (int nt = 0; nt < 4; ++nt) {
            int kg = kt * 64 + nt * 16 + l16;
#pragma unroll
            for (int rg = 0; rg < 4; ++rg) {
                float s = sa[nt][rg] * scale;
                int qg = qbase + quad * 4 + rg;
                if (kg > qg) s = -1e9f;
                sv[nt][rg] = s;
                mt[rg] = fmaxf(mt[rg], s);
            }
        }
        float alpha[4];
#pragma unroll
        for (int rg = 0; rg < 4; ++rg) {
#pragma unroll
            for (int off = 8; off >= 1; off >>= 1)
                mt[rg] = fmaxf(mt[rg], __shfl_xor(mt[rg], off));
            float mn = fmaxf(m_i[rg], mt[rg]);
            alpha[rg] = __expf(m_i[rg] - mn);
            m_i[rg] = mn;
            float rs = 0.f;
#pragma unroll
            for (int nt = 0; nt < 4; ++nt) {
                float p = __expf(sv[nt][rg] - mn);
                sv[nt][rg] = p;
                rs += p;
            }
#pragma unroll
            for (int off = 8; off >= 1; off >>= 1)
                rs += __shfl_xor(rs, off);
            l_i[rg] = l_i[rg] * alpha[rg] + rs;
        }
#pragma unroll
        for (int d = 0; d < 8; ++d)
#pragma unroll
            for (int rg = 0; rg < 4; ++rg)
                acc_o[d][rg] *= alpha[rg];
        // P (C-layout) -> per-wave LDS -> A-layout (same-wave RAW: DS in-order)
#pragma unroll
        for (int nt = 0; nt < 4; ++nt)
#pragma unroll
            for (int rg = 0; rg < 4; ++rg)
                Pw[(quad * 4 + rg) * 72 + nt * 16 + l16] = f2bf(sv[nt][rg]);
        short8 ap0 = *(const short8*)&Pw[l16 * 72 + quad * 8];
        short8 ap1 = *(const short8*)&Pw[l16 * 72 + 32 + quad * 8];
        // PV: VT[dh][key], b[j]=V[key=quad*8+j][dh=l16] contiguous 16B/lane
#pragma unroll
        for (int d = 0; d < 8; ++d) {
            short8 bv0 = *(const short8*)&VTh[(size_t)(d * 16 + l16) * 2048 + kt * 64 + quad * 8];
            acc_o[d] = __builtin_amdgcn_mfma_f32_16x16x32_bf16(ap0, bv0, acc_o[d], 0, 0, 0);
            short8 bv1 = *(const short8*)&VTh[(size_t)(d * 16 + l16) * 2048 + kt * 64 + 32 + quad * 8];
            acc_o[d] = __builtin_amdgcn_mfma_f32_16x16x32_bf16(ap1, bv1, acc_o[d], 0, 0, 0);
        }
    }
#pragma unroll
    for (int d = 0; d < 8; ++d)
#pragma unroll
        for (int rg = 0; rg < 4; ++rg) {
            int s = qbase + quad * 4 + rg;
            Qh[(size_t)s * 128 + d * 16 + l16] = f2bf(acc_o[d][rg] / l_i[rg]);
        }
}

// ================= proj GEMM (m97 structure) =================
// out[4096 x 2048] (fp32) = O * WprojT^T + bias. A read from QO [BH][S][DH].
__global__ __launch_bounds__(256) void gemm_proj(
        const u16* __restrict__ QO, const u16* __restrict__ BT,
        const float* __restrict__ bias, float* __restrict__ out) {
    __shared__ __align__(16) u16 lA[128 * 32];
    __shared__ __align__(16) u16 lB[128 * 32];
    const int tid = threadIdx.x;
    const int lane = tid & 63, wave = tid >> 6;
    const int quad = lane >> 4, l16 = lane & 15;
    const int wm = wave >> 1, wn = wave & 1;
    const int m0 = blockIdx.y * 128, n0 = blockIdx.x * 128;
    f32x4 acc[4][4] = {};
    const int rbase = tid >> 2;
    const int cofs  = (tid & 3) * 8;

    for (int k0 = 0; k0 < 2048; k0 += 32) {
#pragma unroll
        for (int it = 0; it < 2; ++it) {
            int row = m0 + it * 64 + rbase;       // global m
            int b = row >> 11, s = row & 2047;
            int k = k0 + cofs, h = k >> 7, dh = k & 127;
            gl_lds16(QO + ((size_t)(b * 16 + h) * 2048 + s) * 128 + dh, &lA[(it * 256 + tid) * 8]);
            gl_lds16(BT + (size_t)(n0 + it * 64 + rbase) * 2048 + k0 + cofs, &lB[(it * 256 + tid) * 8]);
        }
        __syncthreads();
        short8 af[4], bf[4];
#pragma unroll
        for (int i = 0; i < 4; ++i) {
            af[i] = *(const short8*)&lA[(wm * 64 + i * 16 + l16) * 32 + quad * 8];
            bf[i] = *(const short8*)&lB[(wn * 64 + i * 16 + l16) * 32 + quad * 8];
        }
#pragma unroll
        for (int im = 0; im < 4; ++im)
#pragma unroll
            for (int in = 0; in < 4; ++in)
                acc[im][in] = __builtin_amdgcn_mfma_f32_16x16x32_bf16(af[im], bf[in], acc[im][in], 0, 0, 0);
        __syncthreads();
    }
#pragma unroll
    for (int im = 0; im < 4; ++im) {
        int r0r = m0 + wm * 64 + im * 16 + quad * 4;
#pragma unroll
        for (int in = 0; in < 4; ++in) {
            int cc = n0 + wn * 64 + in * 16 + l16;
            float bv = bias[cc];
#pragma unroll
            for (int rg = 0; rg < 4; ++rg)
                out[(size_t)(r0r + rg) * 2048 + cc] = acc[im][in][rg] + bv;
        }
    }
}

extern "C" void kernel_launch(void* const* d_in, const int* in_sizes, int n_in,
                              void* d_out, int out_size, void* d_ws, size_t ws_size,
                              hipStream_t stream) {
    // match inputs by element count (all distinct)
    const float *x = nullptr, *Wqkv = nullptr, *Wproj = nullptr, *bproj = nullptr;
    for (int i = 0; i < n_in; ++i) {
        int sz = in_sizes[i];
        if      (sz == 2 * 2048 * 2048) x     = (const float*)d_in[i];
        else if (sz == 2048 * 6144)     Wqkv  = (const float*)d_in[i];
        else if (sz == 2048 * 2048)     Wproj = (const float*)d_in[i];
        else if (sz == 2048)            bproj = (const float*)d_in[i];
    }
    float* out = (float*)d_out;

    // ws overlay (92.3 MB peak, all bf16):
    //   xb     [4096][2048]        16.78 MB  -- dead after gemm_qkv; reused for WprojT
    //   WqkvT  [6144][2048]        25.17 MB  -- dead after gemm_qkv
    //   Qb/Ob  [32][2048][128]     16.78 MB
    //   Kb     [32][2048][128]     16.78 MB
    //   VTb    [32][128][2048]     16.78 MB
    u16* xb     = (u16*)d_ws;
    u16* WqkvT  = xb    + (size_t)4096 * 2048;
    u16* Qb     = WqkvT + (size_t)6144 * 2048;
    u16* Kb     = Qb    + (size_t)32 * 2048 * 128;
    u16* VTb    = Kb    + (size_t)32 * 2048 * 128;
    u16* WprojT = xb;   // overlay after xb is dead

    convx<<<dim3(4096), dim3(256), 0, stream>>>(x, xb);
    convT<<<dim3(192, 64), dim3(32, 8), 0, stream>>>(Wqkv, WqkvT, 2048, 6144);
    gemm_qkv<<<dim3(48, 32), dim3(256), 0, stream>>>(xb, WqkvT, Qb, Kb, VTb);
    convT<<<dim3(64, 64), dim3(32, 8), 0, stream>>>(Wproj, WprojT, 2048, 2048);
    attn_kern<<<dim3(32, 32), dim3(256), 0, stream>>>(Qb, Kb, VTb);
    gemm_proj<<<dim3(16, 32), dim3(256), 0, stream>>>(Qb, WprojT, bproj, out);
}

// Round 7
// 485.461 us; speedup vs baseline: 2.3306x; 1.6334x over previous
//
#include <hip/hip_runtime.h>
#include <stdint.h>

typedef __attribute__((ext_vector_type(8))) short short8;
typedef __attribute__((ext_vector_type(4))) float f32x4;
typedef __attribute__((ext_vector_type(4))) unsigned short u16x4;

typedef unsigned short u16;

constexpr int S_LEN = 2048;
constexpr int DH    = 128;

__device__ __forceinline__ u16 f2bf(float f) {
    union { float f; unsigned u; } v; v.f = f;
    unsigned r = v.u + 0x7FFFu + ((v.u >> 16) & 1u);
    return (u16)(r >> 16);
}
__device__ __forceinline__ void gl_lds16(const void* g, void* l) {
    __builtin_amdgcn_global_load_lds((const __attribute__((address_space(1))) void*)g,
                                     (__attribute__((address_space(3))) void*)l,
                                     16, 0, 0);
}

// ---------- fp32 -> bf16 bulk convert ----------
__global__ __launch_bounds__(256) void convx(const float* __restrict__ src,
                                             u16* __restrict__ dst) {
    size_t i = ((size_t)blockIdx.x * 256 + threadIdx.x) * 8;
    f32x4 a = *(const f32x4*)(src + i);
    f32x4 b = *(const f32x4*)(src + i + 4);
    short8 r;
    r[0] = (short)f2bf(a[0]); r[1] = (short)f2bf(a[1]);
    r[2] = (short)f2bf(a[2]); r[3] = (short)f2bf(a[3]);
    r[4] = (short)f2bf(b[0]); r[5] = (short)f2bf(b[1]);
    r[6] = (short)f2bf(b[2]); r[7] = (short)f2bf(b[3]);
    *(short8*)(dst + i) = r;
}

// ---------- fp32 [rows][cols] -> bf16 transposed [cols][rows] ----------
__global__ void convT(const float* __restrict__ src, u16* __restrict__ dst,
                      int rows, int cols) {
    __shared__ u16 tile[32][33];
    int c0 = blockIdx.x * 32, r0 = blockIdx.y * 32;
    int tx = threadIdx.x, ty = threadIdx.y;
#pragma unroll
    for (int i = 0; i < 32; i += 8)
        tile[ty + i][tx] = f2bf(src[(size_t)(r0 + ty + i) * cols + c0 + tx]);
    __syncthreads();
#pragma unroll
    for (int i = 0; i < 32; i += 8)
        dst[(size_t)(c0 + ty + i) * rows + r0 + tx] = tile[tx][ty + i];
}

// ================= QKV GEMM (m97 structure) =================
__global__ __launch_bounds__(256) void gemm_qkv(
        const u16* __restrict__ A, const u16* __restrict__ BT,
        u16* __restrict__ Qo, u16* __restrict__ Ko, u16* __restrict__ VTo) {
    __shared__ __align__(16) u16 lA[128 * 32];
    __shared__ __align__(16) u16 lB[128 * 32];
    const int tid = threadIdx.x;
    const int lane = tid & 63, wave = tid >> 6;
    const int quad = lane >> 4, l16 = lane & 15;
    const int wm = wave >> 1, wn = wave & 1;
    const int m0 = blockIdx.y * 128, n0 = blockIdx.x * 128;
    f32x4 acc[4][4] = {};
    const int rbase = tid >> 2;
    const int cofs  = (tid & 3) * 8;

    for (int k0 = 0; k0 < 2048; k0 += 32) {
#pragma unroll
        for (int it = 0; it < 2; ++it) {
            int row = it * 64 + rbase;
            gl_lds16(A  + (size_t)(m0 + row) * 2048 + k0 + cofs, &lA[(it * 256 + tid) * 8]);
            gl_lds16(BT + (size_t)(n0 + row) * 2048 + k0 + cofs, &lB[(it * 256 + tid) * 8]);
        }
        __syncthreads();
        short8 af[4], bf[4];
#pragma unroll
        for (int i = 0; i < 4; ++i) {
            af[i] = *(const short8*)&lA[(wm * 64 + i * 16 + l16) * 32 + quad * 8];
            bf[i] = *(const short8*)&lB[(wn * 64 + i * 16 + l16) * 32 + quad * 8];
        }
#pragma unroll
        for (int im = 0; im < 4; ++im)
#pragma unroll
            for (int in = 0; in < 4; ++in)
                acc[im][in] = __builtin_amdgcn_mfma_f32_16x16x32_bf16(af[im], bf[in], acc[im][in], 0, 0, 0);
        __syncthreads();
    }
#pragma unroll
    for (int im = 0; im < 4; ++im) {
        int r0r = m0 + wm * 64 + im * 16 + quad * 4;
        int b = r0r >> 11, s0 = r0r & 2047;
#pragma unroll
        for (int in = 0; in < 4; ++in) {
            int cc = n0 + wn * 64 + in * 16 + l16;
            int which = cc >> 11, hd = (cc >> 7) & 15, dh = cc & 127;
            if (which < 2) {
                u16* dst = which == 0 ? Qo : Ko;
#pragma unroll
                for (int rg = 0; rg < 4; ++rg)
                    dst[(size_t)((b * 16 + hd) * 2048 + s0 + rg) * 128 + dh] = f2bf(acc[im][in][rg]);
            } else {
                u16x4 v;
#pragma unroll
                for (int rg = 0; rg < 4; ++rg) v[rg] = f2bf(acc[im][in][rg]);
                *(u16x4*)&VTo[((size_t)(b * 16 + hd) * 128 + dh) * 2048 + s0] = v;
            }
        }
    }
}

// ================= flash attention (causal, LDS-staged, double-buffered) ====
// grid (32,32); qt = 31-blockIdx.x; block 256 = 4 waves; wave w owns 16 q-rows.
// K natural [BH][S][DH]; VT [BH][DH][S]; O overwrites Q in place.
// Per iter: coalesced cooperative staging of K-tile (64x128) and VT-tile
// (128x64) into padded LDS (strides 136/72 u16 = odd x 16B -> 2-way free),
// double-buffered with ONE barrier per iter.
constexpr int KST = 136;   // K LDS row stride (u16)
constexpr int VST = 72;    // VT LDS row stride (u16)

__global__ __launch_bounds__(256) void attn_kern(
        u16* __restrict__ QOp, const u16* __restrict__ Kp,
        const u16* __restrict__ VTp) {
    __shared__ __align__(16) u16 lK[2][64 * KST];
    __shared__ __align__(16) u16 lV[2][128 * VST];
    __shared__ __align__(16) u16 Pl[4][16 * 72];
    const int tid = threadIdx.x, lane = tid & 63, wave = tid >> 6;
    const int quad = lane >> 4, l16 = lane & 15;
    const int qt = 31 - blockIdx.x, bh = blockIdx.y;
    const int qbase = qt * 64 + wave * 16;
    u16* Qh = QOp + (size_t)bh * S_LEN * DH;
    const u16* Kh = Kp + (size_t)bh * S_LEN * DH;
    const u16* VTh = VTp + (size_t)bh * DH * S_LEN;
    u16* Pw = Pl[wave];

    const int krow = tid >> 4, kchunk = tid & 15;   // K: 16 rows/round, 16B chunks
    const int vrow = tid >> 3, vchunk = tid & 7;    // V: 32 rows/round, 16B chunks

    short8 aq[4];
#pragma unroll
    for (int kk = 0; kk < 4; ++kk)
        aq[kk] = *(const short8*)&Qh[(size_t)(qbase + l16) * 128 + kk * 32 + quad * 8];

    f32x4 acc_o[8] = {};
    float m_i[4], l_i[4];
#pragma unroll
    for (int r = 0; r < 4; ++r) { m_i[r] = -1e9f; l_i[r] = 0.f; }
    const float scale = 0.08838834764831845f;  // 1/sqrt(128)

    short8 kr[4], vr[4];
    // prologue: stage tile 0
#pragma unroll
    for (int r = 0; r < 4; ++r) {
        kr[r] = *(const short8*)&Kh[(size_t)(r * 16 + krow) * 128 + kchunk * 8];
        vr[r] = *(const short8*)&VTh[(size_t)(r * 32 + vrow) * 2048 + vchunk * 8];
    }
#pragma unroll
    for (int r = 0; r < 4; ++r) {
        *(short8*)&lK[0][(r * 16 + krow) * KST + kchunk * 8] = kr[r];
        *(short8*)&lV[0][(r * 32 + vrow) * VST + vchunk * 8] = vr[r];
    }
    __syncthreads();

    for (int kt = 0; kt <= qt; ++kt) {
        const int buf = kt & 1;
        const bool more = kt < qt;
        if (more) {   // prefetch next tile into regs (overlaps compute below)
            const size_t kb = (size_t)(kt + 1) * 64;
#pragma unroll
            for (int r = 0; r < 4; ++r) {
                kr[r] = *(const short8*)&Kh[(kb + r * 16 + krow) * 128 + kchunk * 8];
                vr[r] = *(const short8*)&VTh[(size_t)(r * 32 + vrow) * 2048 + kb + vchunk * 8];
            }
        }
        // QK^T from lK[buf]
        f32x4 sa[4] = {};
#pragma unroll
        for (int nt = 0; nt < 4; ++nt)
#pragma unroll
            for (int kk = 0; kk < 4; ++kk) {
                short8 bk = *(const short8*)&lK[buf][(nt * 16 + l16) * KST + kk * 32 + quad * 8];
                sa[nt] = __builtin_amdgcn_mfma_f32_16x16x32_bf16(aq[kk], bk, sa[nt], 0, 0, 0);
            }
        float sv[4][4];
        float mt[4] = {-1e9f, -1e9f, -1e9f, -1e9f};
#pragma unroll
        for (int nt = 0; nt < 4; ++nt) {
            int kg = kt * 64 + nt * 16 + l16;
#pragma unroll
            for (int rg = 0; rg < 4; ++rg) {
                float s = sa[nt][rg] * scale;
                int qg = qbase + quad * 4 + rg;
                if (kg > qg) s = -1e9f;
                sv[nt][rg] = s;
                mt[rg] = fmaxf(mt[rg], s);
            }
        }
        float alpha[4];
#pragma unroll
        for (int rg = 0; rg < 4; ++rg) {
#pragma unroll
            for (int off = 8; off >= 1; off >>= 1)
                mt[rg] = fmaxf(mt[rg], __shfl_xor(mt[rg], off));
            float mn = fmaxf(m_i[rg], mt[rg]);
            alpha[rg] = __expf(m_i[rg] - mn);
            m_i[rg] = mn;
            float rs = 0.f;
#pragma unroll
            for (int nt = 0; nt < 4; ++nt) {
                float p = __expf(sv[nt][rg] - mn);
                sv[nt][rg] = p;
                rs += p;
            }
#pragma unroll
            for (int off = 8; off >= 1; off >>= 1)
                rs += __shfl_xor(rs, off);
            l_i[rg] = l_i[rg] * alpha[rg] + rs;
        }
#pragma unroll
        for (int d = 0; d < 8; ++d)
#pragma unroll
            for (int rg = 0; rg < 4; ++rg)
                acc_o[d][rg] *= alpha[rg];
        // P (C-layout) -> per-wave LDS -> A-layout (same-wave RAW, no barrier)
#pragma unroll
        for (int nt = 0; nt < 4; ++nt)
#pragma unroll
            for (int rg = 0; rg < 4; ++rg)
                Pw[(quad * 4 + rg) * 72 + nt * 16 + l16] = f2bf(sv[nt][rg]);
        short8 ap0 = *(const short8*)&Pw[l16 * 72 + quad * 8];
        short8 ap1 = *(const short8*)&Pw[l16 * 72 + 32 + quad * 8];
        // PV from lV[buf]
#pragma unroll
        for (int d = 0; d < 8; ++d) {
            short8 bv0 = *(const short8*)&lV[buf][(d * 16 + l16) * VST + quad * 8];
            acc_o[d] = __builtin_amdgcn_mfma_f32_16x16x32_bf16(ap0, bv0, acc_o[d], 0, 0, 0);
            short8 bv1 = *(const short8*)&lV[buf][(d * 16 + l16) * VST + 32 + quad * 8];
            acc_o[d] = __builtin_amdgcn_mfma_f32_16x16x32_bf16(ap1, bv1, acc_o[d], 0, 0, 0);
        }
        if (more) {   // write next buffer (other buffer: no conflict with compute)
#pragma unroll
            for (int r = 0; r < 4; ++r) {
                *(short8*)&lK[buf ^ 1][(r * 16 + krow) * KST + kchunk * 8] = kr[r];
                *(short8*)&lV[buf ^ 1][(r * 32 + vrow) * VST + vchunk * 8] = vr[r];
            }
            __syncthreads();
        }
    }
#pragma unroll
    for (int d = 0; d < 8; ++d)
#pragma unroll
        for (int rg = 0; rg < 4; ++rg) {
            int s = qbase + quad * 4 + rg;
            Qh[(size_t)s * 128 + d * 16 + l16] = f2bf(acc_o[d][rg] / l_i[rg]);
        }
}

// ================= proj GEMM (m97 structure, fp32 out) =================
__global__ __launch_bounds__(256) void gemm_proj(
        const u16* __restrict__ QO, const u16* __restrict__ BT,
        const float* __restrict__ bias, float* __restrict__ out) {
    __shared__ __align__(16) u16 lA[128 * 32];
    __shared__ __align__(16) u16 lB[128 * 32];
    const int tid = threadIdx.x;
    const int lane = tid & 63, wave = tid >> 6;
    const int quad = lane >> 4, l16 = lane & 15;
    const int wm = wave >> 1, wn = wave & 1;
    const int m0 = blockIdx.y * 128, n0 = blockIdx.x * 128;
    f32x4 acc[4][4] = {};
    const int rbase = tid >> 2;
    const int cofs  = (tid & 3) * 8;

    for (int k0 = 0; k0 < 2048; k0 += 32) {
#pragma unroll
        for (int it = 0; it < 2; ++it) {
            int row = m0 + it * 64 + rbase;
            int b = row >> 11, s = row & 2047;
            int k = k0 + cofs, h = k >> 7, dh = k & 127;
            gl_lds16(QO + ((size_t)(b * 16 + h) * 2048 + s) * 128 + dh, &lA[(it * 256 + tid) * 8]);
            gl_lds16(BT + (size_t)(n0 + it * 64 + rbase) * 2048 + k0 + cofs, &lB[(it * 256 + tid) * 8]);
        }
        __syncthreads();
        short8 af[4], bf[4];
#pragma unroll
        for (int i = 0; i < 4; ++i) {
            af[i] = *(const short8*)&lA[(wm * 64 + i * 16 + l16) * 32 + quad * 8];
            bf[i] = *(const short8*)&lB[(wn * 64 + i * 16 + l16) * 32 + quad * 8];
        }
#pragma unroll
        for (int im = 0; im < 4; ++im)
#pragma unroll
            for (int in = 0; in < 4; ++in)
                acc[im][in] = __builtin_amdgcn_mfma_f32_16x16x32_bf16(af[im], bf[in], acc[im][in], 0, 0, 0);
        __syncthreads();
    }
#pragma unroll
    for (int im = 0; im < 4; ++im) {
        int r0r = m0 + wm * 64 + im * 16 + quad * 4;
#pragma unroll
        for (int in = 0; in < 4; ++in) {
            int cc = n0 + wn * 64 + in * 16 + l16;
            float bv = bias[cc];
#pragma unroll
            for (int rg = 0; rg < 4; ++rg)
                out[(size_t)(r0r + rg) * 2048 + cc] = acc[im][in][rg] + bv;
        }
    }
}

extern "C" void kernel_launch(void* const* d_in, const int* in_sizes, int n_in,
                              void* d_out, int out_size, void* d_ws, size_t ws_size,
                              hipStream_t stream) {
    const float *x = nullptr, *Wqkv = nullptr, *Wproj = nullptr, *bproj = nullptr;
    for (int i = 0; i < n_in; ++i) {
        int sz = in_sizes[i];
        if      (sz == 2 * 2048 * 2048) x     = (const float*)d_in[i];
        else if (sz == 2048 * 6144)     Wqkv  = (const float*)d_in[i];
        else if (sz == 2048 * 2048)     Wproj = (const float*)d_in[i];
        else if (sz == 2048)            bproj = (const float*)d_in[i];
    }
    float* out = (float*)d_out;

    // ws overlay (92.3 MB peak, all bf16)
    u16* xb     = (u16*)d_ws;
    u16* WqkvT  = xb    + (size_t)4096 * 2048;
    u16* Qb     = WqkvT + (size_t)6144 * 2048;
    u16* Kb     = Qb    + (size_t)32 * 2048 * 128;
    u16* VTb    = Kb    + (size_t)32 * 2048 * 128;
    u16* WprojT = xb;   // overlay after xb dead

    convx<<<dim3(4096), dim3(256), 0, stream>>>(x, xb);
    convT<<<dim3(192, 64), dim3(32, 8), 0, stream>>>(Wqkv, WqkvT, 2048, 6144);
    gemm_qkv<<<dim3(48, 32), dim3(256), 0, stream>>>(xb, WqkvT, Qb, Kb, VTb);
    convT<<<dim3(64, 64), dim3(32, 8), 0, stream>>>(Wproj, WprojT, 2048, 2048);
    attn_kern<<<dim3(32, 32), dim3(256), 0, stream>>>(Qb, Kb, VTb);
    gemm_proj<<<dim3(16, 32), dim3(256), 0, stream>>>(Qb, WprojT, bproj, out);
}